// Round 6
// baseline (369.923 us; speedup 1.0000x reference)
//
#include <hip/hip_runtime.h>
#include <hip/hip_bf16.h>

// MetaAdaptiveFusion: B=32, N=2048, H=256, F=8 fusion heads, NH=8, dh=32, 3 meta steps.
//
// Final dtype model (6-round evidence):
//  - Device inputs: fp32 buffers holding bf16-QUANTIZED values (bf16 reads NaN ->
//    data is fp32; "(bf16)" label + bf16-representable ref-max -> values quantized).
//  - Device output: fp32 (reference returns float32; harness doc: "else float*").
//    R2/R4's bit-identical wrong absmax == bf16-written-into-fp32-buffer scramble.
//  - ws_size: irrelevant to past failures; 3.52 MB layout kept (known to launch).
//
// Algebra (exact linear-algebra folds, fp32 math):
//   u = qh^T Wk / sqrt(dh); bk cancels in softmax; w = sum_n attn*cw*docs;
//   ctx = Wv w + bv; ho = Wo ctx + bo; 3 residual meta steps; strategy combine.

#define B_ 32
#define N_ 2048
#define H_ 256
#define F_ 8
#define NH_ 8
#define DH_ 32
#define FH_ 64   // F_*NH_
#define STEPS_ 3
#define NCHUNK_ 16   // 16 chunks of 128 docs

typedef __hip_bfloat16 bf16;
__device__ __forceinline__ float b2f(bf16 x) { return __bfloat162float(x); }

// ---- ws byte layout (total 3,687,424 B = 3.52 MB) ----
static constexpr size_t UB_U     = 0;          // bf16 [B][FH][H]   1,048,576 B
static constexpr size_t UB_W     = 1048576;    // f32  [B][FH][H]   2,097,152 B
static constexpr size_t UB_PM    = 3145728;    // f32  [B*FH][16]     131,072 B
static constexpr size_t UB_PL    = 3276800;    // f32  [B*FH][16]     131,072 B
static constexpr size_t UB_M     = 3407872;    // f32  [B*FH]           8,192 B
static constexpr size_t UB_L     = 3416064;    // f32  [B*FH]           8,192 B
static constexpr size_t UB_STRAT = 3424256;    // f32  [B][F]           1,024 B
static constexpr size_t UB_HO    = 3425280;    // f32  [F][B][H]      262,144 B
static constexpr size_t WS_NEEDED = 3687424;

// K1: qh, u = qh^T Wk / sqrt(dh) (stored bf16 — values are bf16-scale anyway),
//     strategy softmax
__global__ __launch_bounds__(256) void k1_prep(
    const float* __restrict__ query, const float* __restrict__ ipw,
    const float* __restrict__ ipb, const float* __restrict__ stw,
    const float* __restrict__ stb, bf16* __restrict__ u,
    float* __restrict__ strat)
{
  const int bid = blockIdx.x;
  const int f = bid & 7, b = bid >> 3;
  const int tid = threadIdx.x;
  __shared__ float q_s[H_];
  __shared__ float qh_s[H_];
  __shared__ float logit_s[F_];

  q_s[tid] = query[b * H_ + tid];
  __syncthreads();

  {  // qh[tid] = q . Wq[tid,:] + bq[tid]
    const float* row = ipw + ((size_t)f * 3 * H_ + tid) * H_;
    float acc = ipb[f * 3 * H_ + tid];
    #pragma unroll 8
    for (int k = 0; k < H_; ++k) acc += q_s[k] * row[k];
    qh_s[tid] = acc;
  }
  if (f == 0 && tid < F_) {
    float acc = stb[tid];
    const float* row = stw + tid * H_;
    for (int k = 0; k < H_; ++k) acc += q_s[k] * row[k];
    logit_s[tid] = acc;
  }
  __syncthreads();

  {  // u[b][f*8+h][tid]
    const float* Wk = ipw + ((size_t)f * 3 * H_ + H_) * H_;
    const float scale = 0.17677669529663687f;  // 1/sqrt(32)
    bf16* uout = u + ((size_t)b * FH_ + f * NH_) * H_ + tid;
    for (int h = 0; h < NH_; ++h) {
      float acc = 0.f;
      #pragma unroll 8
      for (int d = 0; d < DH_; ++d) {
        int r = h * DH_ + d;
        acc += qh_s[r] * Wk[(size_t)r * H_ + tid];
      }
      uout[(size_t)h * H_] = __float2bfloat16(acc * scale);
    }
  }
  if (f == 0 && tid == 0) {
    float mx = logit_s[0];
    #pragma unroll
    for (int i = 1; i < F_; ++i) mx = fmaxf(mx, logit_s[i]);
    float s = 0.f, e[F_];
    #pragma unroll
    for (int i = 0; i < F_; ++i) { e[i] = __expf(logit_s[i] - mx); s += e[i]; }
    #pragma unroll
    for (int i = 0; i < F_; ++i) strat[b * F_ + i] = e[i] / s;
  }
}

// K2: per-(row,chunk) softmax partials. s[fh][n] = cw[n]*(docs[n,:].u[fh,:])
__global__ __launch_bounds__(256) void k2_stats(
    const float* __restrict__ docs, const float* __restrict__ cw,
    const bf16* __restrict__ u, float* __restrict__ pm, float* __restrict__ pl)
{
  const int c = blockIdx.x, b = blockIdx.y;
  const int n0 = c * 128;
  const int tid = threadIdx.x;
  const int tn = tid & 31, tf = tid >> 5;
  __shared__ float sd[128 * 33];
  __shared__ float su[64 * 33];

  float acc[4][8];
  #pragma unroll
  for (int a = 0; a < 4; ++a)
    #pragma unroll
    for (int e = 0; e < 8; ++e) acc[a][e] = 0.f;

  for (int j0 = 0; j0 < H_; j0 += 32) {
    __syncthreads();
    #pragma unroll
    for (int i = 0; i < 16; ++i) {
      int idx = tid + 256 * i;
      int jj = idx & 31, nn = idx >> 5;
      sd[nn * 33 + jj] = docs[((size_t)b * N_ + n0 + nn) * H_ + j0 + jj];
    }
    #pragma unroll
    for (int i = 0; i < 8; ++i) {
      int idx = tid + 256 * i;
      int jj = idx & 31, fh = idx >> 5;
      su[fh * 33 + jj] = b2f(u[((size_t)b * FH_ + fh) * H_ + j0 + jj]);
    }
    __syncthreads();
    #pragma unroll 4
    for (int jj = 0; jj < 32; ++jj) {
      float d[4], uv[8];
      #pragma unroll
      for (int a = 0; a < 4; ++a) d[a] = sd[(tn + 32 * a) * 33 + jj];
      #pragma unroll
      for (int e = 0; e < 8; ++e) uv[e] = su[(tf + 8 * e) * 33 + jj];
      #pragma unroll
      for (int a = 0; a < 4; ++a)
        #pragma unroll
        for (int e = 0; e < 8; ++e) acc[a][e] += d[a] * uv[e];
    }
  }
  float cwv[4];
  #pragma unroll
  for (int a = 0; a < 4; ++a) cwv[a] = cw[b * N_ + n0 + tn + 32 * a];

  #pragma unroll
  for (int e = 0; e < 8; ++e) {
    float s[4];
    #pragma unroll
    for (int a = 0; a < 4; ++a) s[a] = acc[a][e] * cwv[a];
    float mx = fmaxf(fmaxf(s[0], s[1]), fmaxf(s[2], s[3]));
    #pragma unroll
    for (int off = 16; off > 0; off >>= 1) mx = fmaxf(mx, __shfl_xor(mx, off, 32));
    float se = 0.f;
    #pragma unroll
    for (int a = 0; a < 4; ++a) se += __expf(s[a] - mx);
    #pragma unroll
    for (int off = 16; off > 0; off >>= 1) se += __shfl_xor(se, off, 32);
    if (tn == 0) {
      int row = b * FH_ + tf + 8 * e;
      pm[(size_t)row * NCHUNK_ + c] = mx;
      pl[(size_t)row * NCHUNK_ + c] = se;
    }
  }
}

// K3: merge chunk partials
__global__ __launch_bounds__(256) void k3_merge(
    const float* __restrict__ pm, const float* __restrict__ pl,
    float* __restrict__ wm, float* __restrict__ wl)
{
  const int row = blockIdx.x * 256 + threadIdx.x;
  float v[NCHUNK_];
  #pragma unroll
  for (int c = 0; c < NCHUNK_; ++c) v[c] = pm[(size_t)row * NCHUNK_ + c];
  float m = v[0];
  #pragma unroll
  for (int c = 1; c < NCHUNK_; ++c) m = fmaxf(m, v[c]);
  float l = 0.f;
  #pragma unroll
  for (int c = 0; c < NCHUNK_; ++c)
    l += pl[(size_t)row * NCHUNK_ + c] * __expf(v[c] - m);
  wm[row] = m;
  wl[row] = 1.f / l;
}

// K4: recompute scores, accumulate w += attn*cw*docs (atomic over chunks)
__global__ __launch_bounds__(256) void k4_waccum(
    const float* __restrict__ docs, const float* __restrict__ cw,
    const bf16* __restrict__ u, const float* __restrict__ wm,
    const float* __restrict__ wl, float* __restrict__ w)
{
  const int c = blockIdx.x, b = blockIdx.y;
  const int n0 = c * 128;
  const int tid = threadIdx.x;
  const int tn = tid & 31, tf = tid >> 5;
  __shared__ float sp[128 * 65];
  __shared__ float sbuf[32 * 256];
  __shared__ float sm[FH_], sl[FH_];
  if (tid < FH_) { sm[tid] = wm[b * FH_ + tid]; sl[tid] = wl[b * FH_ + tid]; }

  float* sd = sbuf;
  float* su = sbuf + 128 * 33;

  float acc[4][8];
  #pragma unroll
  for (int a = 0; a < 4; ++a)
    #pragma unroll
    for (int e = 0; e < 8; ++e) acc[a][e] = 0.f;

  for (int j0 = 0; j0 < H_; j0 += 32) {
    __syncthreads();
    #pragma unroll
    for (int i = 0; i < 16; ++i) {
      int idx = tid + 256 * i;
      int jj = idx & 31, nn = idx >> 5;
      sd[nn * 33 + jj] = docs[((size_t)b * N_ + n0 + nn) * H_ + j0 + jj];
    }
    #pragma unroll
    for (int i = 0; i < 8; ++i) {
      int idx = tid + 256 * i;
      int jj = idx & 31, fh = idx >> 5;
      su[fh * 33 + jj] = b2f(u[((size_t)b * FH_ + fh) * H_ + j0 + jj]);
    }
    __syncthreads();
    #pragma unroll 4
    for (int jj = 0; jj < 32; ++jj) {
      float d[4], uv[8];
      #pragma unroll
      for (int a = 0; a < 4; ++a) d[a] = sd[(tn + 32 * a) * 33 + jj];
      #pragma unroll
      for (int e = 0; e < 8; ++e) uv[e] = su[(tf + 8 * e) * 33 + jj];
      #pragma unroll
      for (int a = 0; a < 4; ++a)
        #pragma unroll
        for (int e = 0; e < 8; ++e) acc[a][e] += d[a] * uv[e];
    }
  }
  float cwv[4];
  #pragma unroll
  for (int a = 0; a < 4; ++a) cwv[a] = cw[b * N_ + n0 + tn + 32 * a];
  #pragma unroll
  for (int e = 0; e < 8; ++e) {
    int fh = tf + 8 * e;
    #pragma unroll
    for (int a = 0; a < 4; ++a) {
      float p = __expf(acc[a][e] * cwv[a] - sm[fh]) * sl[fh] * cwv[a];
      sp[(tn + 32 * a) * 65 + fh] = p;
    }
  }
  __syncthreads();

  float acc2[8][8];
  #pragma unroll
  for (int e = 0; e < 8; ++e)
    #pragma unroll
    for (int a = 0; a < 8; ++a) acc2[e][a] = 0.f;

  for (int ns = 0; ns < 128; ns += 32) {
    #pragma unroll
    for (int i = 0; i < 32; ++i) {
      int idx = tid + 256 * i;
      int j = idx & 255, nn = idx >> 8;
      sbuf[nn * 256 + j] = docs[((size_t)b * N_ + n0 + ns + nn) * H_ + j];
    }
    __syncthreads();
    for (int nn = 0; nn < 32; ++nn) {
      float pv[8], dv[8];
      #pragma unroll
      for (int e = 0; e < 8; ++e) pv[e] = sp[(ns + nn) * 65 + tf + 8 * e];
      #pragma unroll
      for (int a = 0; a < 8; ++a) dv[a] = sbuf[nn * 256 + tn + 32 * a];
      #pragma unroll
      for (int e = 0; e < 8; ++e)
        #pragma unroll
        for (int a = 0; a < 8; ++a) acc2[e][a] += pv[e] * dv[a];
    }
    __syncthreads();
  }
  #pragma unroll
  for (int e = 0; e < 8; ++e)
    #pragma unroll
    for (int a = 0; a < 8; ++a)
      atomicAdd(&w[((size_t)b * FH_ + tf + 8 * e) * H_ + tn + 32 * a], acc2[e][a]);
}

// K5: ctx = Wv w + bv; ho = Wo ctx + bo; 3 residual meta steps
__global__ __launch_bounds__(256) void k5_headout(
    const float* __restrict__ ipw, const float* __restrict__ ipb,
    const float* __restrict__ opw, const float* __restrict__ opb,
    const float* __restrict__ meta, const float* __restrict__ w,
    float* __restrict__ ho)
{
  const int bid = blockIdx.x;
  const int f = bid & 7, b = bid >> 3;
  const int tid = threadIdx.x;
  __shared__ float sw_[NH_ * H_];
  __shared__ float sctx[H_];
  __shared__ float sho[H_];
  #pragma unroll
  for (int i = 0; i < 8; ++i)
    sw_[i * 256 + tid] = w[((size_t)b * FH_ + f * NH_) * H_ + i * 256 + tid];
  __syncthreads();
  {
    const int r = tid, h = r >> 5;
    const float* wvrow = ipw + ((size_t)f * 3 * H_ + 2 * H_ + r) * H_;
    float acc = ipb[f * 3 * H_ + 2 * H_ + r];
    #pragma unroll 8
    for (int j = 0; j < H_; ++j) acc += wvrow[j] * sw_[h * H_ + j];
    sctx[r] = acc;
  }
  __syncthreads();
  {
    const float* worow = opw + ((size_t)f * H_ + tid) * H_;
    float acc = opb[f * H_ + tid];
    #pragma unroll 8
    for (int j = 0; j < H_; ++j) acc += worow[j] * sctx[j];
    sho[tid] = acc;
  }
  __syncthreads();
  for (int s = 0; s < STEPS_; ++s) {
    const float* M = meta + (size_t)s * H_ * H_;
    float acc = sho[tid];
    #pragma unroll 8
    for (int r = 0; r < H_; ++r) acc += sho[r] * M[(size_t)r * H_ + tid];
    __syncthreads();
    sho[tid] = acc;
    __syncthreads();
  }
  ho[((size_t)f * B_ + b) * H_ + tid] = sho[tid];
}

// K6: combine -> fp32 output (reference returns float32)
__global__ __launch_bounds__(256) void k6_combine(
    const float* __restrict__ ho, const float* __restrict__ strat,
    float* __restrict__ out)
{
  const int b = blockIdx.x;
  const int tid = threadIdx.x;
  float acc = 0.f;
  #pragma unroll
  for (int f = 0; f < F_; ++f)
    acc += strat[b * F_ + f] * ho[((size_t)f * B_ + b) * H_ + tid];
  out[b * H_ + tid] = acc;
}

extern "C" void kernel_launch(void* const* d_in, const int* in_sizes, int n_in,
                              void* d_out, int out_size, void* d_ws, size_t ws_size,
                              hipStream_t stream) {
  const float* query = (const float*)d_in[0];
  const float* docs  = (const float*)d_in[1];
  const float* cw    = (const float*)d_in[2];
  // d_in[3] context_history: unused by the reference
  const float* ipw   = (const float*)d_in[4];
  const float* ipb   = (const float*)d_in[5];
  const float* opw   = (const float*)d_in[6];
  const float* opb   = (const float*)d_in[7];
  const float* stw   = (const float*)d_in[8];
  const float* stb   = (const float*)d_in[9];
  const float* meta  = (const float*)d_in[10];
  float* out = (float*)d_out;

  char* base = (char*)d_ws;
  bf16*  u     = (bf16*)(base + UB_U);
  float* w     = (float*)(base + UB_W);
  float* pm    = (float*)(base + UB_PM);
  float* pl    = (float*)(base + UB_PL);
  float* wm    = (float*)(base + UB_M);
  float* wl    = (float*)(base + UB_L);
  float* strat = (float*)(base + UB_STRAT);
  float* ho    = (float*)(base + UB_HO);

  // zero the w accumulator (ws is poisoned 0xAA before every launch)
  hipMemsetAsync(w, 0, (size_t)B_ * FH_ * H_ * sizeof(float), stream);

  k1_prep<<<dim3(F_ * B_), 256, 0, stream>>>(query, ipw, ipb, stw, stb, u, strat);
  k2_stats<<<dim3(NCHUNK_, B_), 256, 0, stream>>>(docs, cw, u, pm, pl);
  k3_merge<<<dim3(B_ * FH_ / 256), 256, 0, stream>>>(pm, pl, wm, wl);
  k4_waccum<<<dim3(NCHUNK_, B_), 256, 0, stream>>>(docs, cw, u, wm, wl, w);
  k5_headout<<<dim3(F_ * B_), 256, 0, stream>>>(ipw, ipb, opw, opb, meta, w, ho);
  k6_combine<<<dim3(B_), 256, 0, stream>>>(ho, strat, out);
}

// Round 8
// 363.644 us; speedup vs baseline: 1.0173x; 1.0173x over previous
//
#include <hip/hip_runtime.h>
#include <hip/hip_bf16.h>

// MetaAdaptiveFusion: B=32, N=2048, H=256, F=8, NH=8, dh=32, 3 meta steps.
// Inputs: fp32 buffers holding bf16-quantized values -> bf16 casts are LOSSLESS,
// so the two docs-sized passes (scores, P^T*docs) run on MFMA bf16 exactly.
// Output fp32. Internal accumulation fp32. P is split p_hi+p_lo (2 MFMAs) to keep
// ~fp32 accuracy through the value accumulation.
//
// R7 bug fixed here: k2 docs staging covered only 64 of 128 tile rows (p<4 -> p<8);
// rows 64..127 were uninitialized LDS -> NaN. All MFMA fragment indexing re-audited
// against the verified gfx950 layouts (A: m=lane&15,k=(lane>>4)*8+j; D: col=lane&15,
// row=(lane>>4)*4+reg) — unchanged.
//
// Pipeline: memset(w) ; k1 (qh, u=qh^T Wk/sqrt(dh) bf16, strategy softmax)
//           k2 (MFMA scores -> per-chunk softmax partials pm/pl)
//           k4 (merge partials; MFMA scores recompute; p hi/lo; MFMA p*docs -> w atomics)
//           k5 (ctx=Wv w+bv; ho=Wo ctx+bo; 3 residual meta steps)  k6 (strategy combine)

#define B_ 32
#define N_ 2048
#define H_ 256
#define F_ 8
#define FH_ 64
#define NCH2_ 16   // k2: 16 chunks of 128 docs

typedef unsigned short u16;
typedef __attribute__((ext_vector_type(8))) short bf16x8;   // 8 bf16 (4 VGPRs)
typedef __attribute__((ext_vector_type(4))) float f32x4;
#define MFMA(a, b, c) __builtin_amdgcn_mfma_f32_16x16x32_bf16((a), (b), (c), 0, 0, 0)

__device__ __forceinline__ u16 f2b(float x) {   // fp32 -> bf16 bits, RNE
  unsigned u = __builtin_bit_cast(unsigned, x);
  return (u16)((u + 0x7fffu + ((u >> 16) & 1u)) >> 16);
}
__device__ __forceinline__ float b2f(u16 h) {
  unsigned u = ((unsigned)h) << 16;
  return __builtin_bit_cast(float, u);
}

// ---- ws byte layout (3,687,424 B total, proven safe in R6) ----
static constexpr size_t UB_U     = 0;          // u16 [B][FH][H]    1,048,576
static constexpr size_t UB_W     = 1048576;    // f32 [B][FH][H]    2,097,152
static constexpr size_t UB_PM    = 3145728;    // f32 [B*FH][16]      131,072
static constexpr size_t UB_PL    = 3276800;    // f32 [B*FH][16]      131,072
static constexpr size_t UB_STRAT = 3424256;    // f32 [B][F]            1,024
static constexpr size_t UB_HO    = 3425280;    // f32 [F][B][H]       262,144

// =============== K1: qh, u, strategy (coalesced wave-per-row dots) ===============
__global__ __launch_bounds__(256) void k1_prep(
    const float* __restrict__ query, const float* __restrict__ ipw,
    const float* __restrict__ ipb, const float* __restrict__ stw,
    const float* __restrict__ stb, u16* __restrict__ u, float* __restrict__ strat)
{
  const int f = blockIdx.x & 7, b = blockIdx.x >> 3;
  const int tid = threadIdx.x, L = tid & 63, w = tid >> 6;
  __shared__ float qh_s[H_];
  __shared__ float logit_s[F_];

  float4 qv = *(const float4*)&query[b * H_ + L * 4];

  // qh rows: wave w handles rows w*64..w*64+63; lane-parallel dot + butterfly
  for (int rr = 0; rr < 64; ++rr) {
    int r = w * 64 + rr;
    float4 a = *(const float4*)&ipw[((size_t)(f * 768) + r) * H_ + L * 4];
    float d = a.x * qv.x + a.y * qv.y + a.z * qv.z + a.w * qv.w;
    #pragma unroll
    for (int m = 32; m; m >>= 1) d += __shfl_xor(d, m, 64);
    if (L == rr) qh_s[r] = d + ipb[f * 768 + r];
  }
  if (f == 0 && w == 0) {  // strategy logits, 8 rows
    for (int rr = 0; rr < 8; ++rr) {
      float4 a = *(const float4*)&stw[rr * H_ + L * 4];
      float d = a.x * qv.x + a.y * qv.y + a.z * qv.z + a.w * qv.w;
      #pragma unroll
      for (int m = 32; m; m >>= 1) d += __shfl_xor(d, m, 64);
      if (L == rr) logit_s[rr] = d + stb[rr];
    }
  }
  __syncthreads();

  // u[b][f*8+h][tid] = (1/sqrt(32)) * sum_d qh[h*32+d] * Wk[h*32+d][tid]  (coalesced)
  const float scale = 0.17677669529663687f;
  for (int h = 0; h < 8; ++h) {
    float acc = 0.f;
    #pragma unroll 8
    for (int d0 = 0; d0 < 32; ++d0) {
      int r = h * 32 + d0;
      acc += qh_s[r] * ipw[((size_t)(f * 768 + 256) + r) * H_ + tid];
    }
    u[((size_t)(b * 64) + f * 8 + h) * H_ + tid] = f2b(acc * scale);
  }
  if (f == 0 && tid == 0) {
    float mx = logit_s[0];
    #pragma unroll
    for (int i = 1; i < F_; ++i) mx = fmaxf(mx, logit_s[i]);
    float s = 0.f, e[F_];
    #pragma unroll
    for (int i = 0; i < F_; ++i) { e[i] = __expf(logit_s[i] - mx); s += e[i]; }
    #pragma unroll
    for (int i = 0; i < F_; ++i) strat[b * F_ + i] = e[i] / s;
  }
}

// =============== K2: MFMA scores -> chunk softmax partials =======================
// grid (16, 32): chunk c = 128 docs. Wave w: rows w*32..+32 (2 M-tiles) x 64 fh.
__global__ __launch_bounds__(256) void k2_stats(
    const float* __restrict__ docs, const float* __restrict__ cw,
    const u16* __restrict__ u, float* __restrict__ pm, float* __restrict__ pl)
{
  const int c = blockIdx.x, b = blockIdx.y;
  const int n0 = c * 128;
  const int tid = threadIdx.x, L = tid & 63, w = tid >> 6;
  const int khi = L >> 4, col = L & 15;

  __shared__ bf16x8 sd8[128 * 9];   // docs chunk [128 n][72 j] bf16 (rows = 9 x b128)
  __shared__ bf16x8 su8[64 * 9];    // u chunk [64 fh][72 j]
  __shared__ float scw[128];
  __shared__ float swred[4][64];
  __shared__ float sbm[64];
  u16* sdu = (u16*)sd8;

  if (tid < 128) scw[tid] = cw[b * N_ + n0 + tid];

  f32x4 acc[2][4];
  #pragma unroll
  for (int t = 0; t < 2; ++t)
    #pragma unroll
    for (int nt = 0; nt < 4; ++nt) acc[t][nt] = (f32x4){0.f, 0.f, 0.f, 0.f};

  for (int j0 = 0; j0 < 256; j0 += 64) {
    if (j0) __syncthreads();
    #pragma unroll
    for (int p = 0; p < 8; ++p) {   // docs [128 n][64 j] fp32 -> bf16 (FIXED: p<8)
      int idx = tid + 256 * p;
      int n = idx >> 4, jq = (idx & 15) * 4;
      float4 v = *(const float4*)&docs[((size_t)(b * N_) + n0 + n) * H_ + j0 + jq];
      *(ushort4*)&sdu[n * 72 + jq] = make_ushort4(f2b(v.x), f2b(v.y), f2b(v.z), f2b(v.w));
    }
    #pragma unroll
    for (int p = 0; p < 2; ++p) {   // u [64][64]
      int idx = tid + 256 * p;
      int fh = idx >> 3, sub = idx & 7;
      su8[fh * 9 + sub] = *(const bf16x8*)&u[((size_t)(b * 64) + fh) * H_ + j0 + sub * 8];
    }
    __syncthreads();
    #pragma unroll
    for (int kk = 0; kk < 64; kk += 32) {
      bf16x8 a0 = sd8[(w * 32 + col) * 9 + kk / 8 + khi];
      bf16x8 a1 = sd8[(w * 32 + 16 + col) * 9 + kk / 8 + khi];
      #pragma unroll
      for (int nt = 0; nt < 4; ++nt) {
        bf16x8 bb = su8[(nt * 16 + col) * 9 + kk / 8 + khi];
        acc[0][nt] = MFMA(a0, bb, acc[0][nt]);
        acc[1][nt] = MFMA(a1, bb, acc[1][nt]);
      }
    }
  }
  // s = raw * cw ; chunk max / sum-exp per fh
  float cwv[2][4];
  #pragma unroll
  for (int t = 0; t < 2; ++t)
    #pragma unroll
    for (int r = 0; r < 4; ++r) cwv[t][r] = scw[w * 32 + t * 16 + khi * 4 + r];

  float mx[4];
  #pragma unroll
  for (int nt = 0; nt < 4; ++nt) {
    mx[nt] = -3.4e38f;
    #pragma unroll
    for (int t = 0; t < 2; ++t)
      #pragma unroll
      for (int r = 0; r < 4; ++r) {
        float sv = acc[t][nt][r] * cwv[t][r];
        acc[t][nt][r] = sv;
        mx[nt] = fmaxf(mx[nt], sv);
      }
    mx[nt] = fmaxf(mx[nt], __shfl_xor(mx[nt], 16, 64));
    mx[nt] = fmaxf(mx[nt], __shfl_xor(mx[nt], 32, 64));
  }
  if (L < 16) {
    #pragma unroll
    for (int nt = 0; nt < 4; ++nt) swred[w][nt * 16 + L] = mx[nt];
  }
  __syncthreads();
  if (tid < 64)
    sbm[tid] = fmaxf(fmaxf(swred[0][tid], swred[1][tid]),
                     fmaxf(swred[2][tid], swred[3][tid]));
  __syncthreads();
  float ls[4];
  #pragma unroll
  for (int nt = 0; nt < 4; ++nt) {
    float bm = sbm[nt * 16 + col];
    ls[nt] = 0.f;
    #pragma unroll
    for (int t = 0; t < 2; ++t)
      #pragma unroll
      for (int r = 0; r < 4; ++r) ls[nt] += __expf(acc[t][nt][r] - bm);
    ls[nt] += __shfl_xor(ls[nt], 16, 64);
    ls[nt] += __shfl_xor(ls[nt], 32, 64);
  }
  __syncthreads();
  if (L < 16) {
    #pragma unroll
    for (int nt = 0; nt < 4; ++nt) swred[w][nt * 16 + L] = ls[nt];
  }
  __syncthreads();
  if (tid < 64) {
    float bl = swred[0][tid] + swred[1][tid] + swred[2][tid] + swred[3][tid];
    size_t ro = (size_t)(b * 64 + tid) * NCH2_ + c;
    pm[ro] = sbm[tid];
    pl[ro] = bl;
  }
}

// =============== K4: merge partials; scores; p hi/lo; MFMA p*docs -> w ===========
// grid (32, 32): chunk = 64 docs. LDS ~62 KB (fits 64 KB budget, 2 blocks/CU).
__global__ __launch_bounds__(256) void k4_waccum(
    const float* __restrict__ docs, const float* __restrict__ cw,
    const u16* __restrict__ u, const float* __restrict__ pm,
    const float* __restrict__ pl, float* __restrict__ wbuf)
{
  const int c = blockIdx.x, b = blockIdx.y;
  const int n0 = c * 64;
  const int tid = threadIdx.x, L = tid & 63, w = tid >> 6;
  const int khi = L >> 4, col = L & 15;

  __shared__ bf16x8 sdoc8[64 * 33];   // docs [64 n][264 j] bf16
  __shared__ bf16x8 su8[64 * 9];      // u chunk [64 fh][72 j]
  __shared__ bf16x8 ph8[64 * 9];      // p_hi  [64 fh][72 n]
  __shared__ bf16x8 plo8[64 * 9];     // p_lo
  __shared__ float scw[64];
  __shared__ float sm_l[64], sl_l[64];
  u16* sdu  = (u16*)sdoc8;
  u16* phu  = (u16*)ph8;
  u16* plou = (u16*)plo8;

  if (tid < 64) scw[tid] = cw[b * N_ + n0 + tid];
  if (tid >= 64 && tid < 128) {   // fold k3: global m, 1/l per fh from chunk partials
    int fh = tid - 64;
    size_t ro = (size_t)(b * 64 + fh) * NCH2_;
    float m = pm[ro];
    for (int cc = 1; cc < NCH2_; ++cc) m = fmaxf(m, pm[ro + cc]);
    float l = 0.f;
    for (int cc = 0; cc < NCH2_; ++cc) l += pl[ro + cc] * __expf(pm[ro + cc] - m);
    sm_l[fh] = m;
    sl_l[fh] = 1.f / l;
  }
  #pragma unroll
  for (int p = 0; p < 16; ++p) {   // docs [64][256] fp32 -> bf16, coalesced
    int idx = tid + 256 * p;
    int n = idx >> 6, jq = (idx & 63) * 4;
    float4 v = *(const float4*)&docs[((size_t)(b * N_) + n0 + n) * H_ + jq];
    *(ushort4*)&sdu[n * 264 + jq] = make_ushort4(f2b(v.x), f2b(v.y), f2b(v.z), f2b(v.w));
  }
  __syncthreads();

  // phase A: scores for wave's 16 rows (M-tile w) x 64 fh
  f32x4 acc[4];
  #pragma unroll
  for (int nt = 0; nt < 4; ++nt) acc[nt] = (f32x4){0.f, 0.f, 0.f, 0.f};

  for (int j0 = 0; j0 < 256; j0 += 64) {
    #pragma unroll
    for (int p = 0; p < 2; ++p) {
      int idx = tid + 256 * p;
      int fh = idx >> 3, sub = idx & 7;
      su8[fh * 9 + sub] = *(const bf16x8*)&u[((size_t)(b * 64) + fh) * H_ + j0 + sub * 8];
    }
    __syncthreads();
    #pragma unroll
    for (int kk = 0; kk < 64; kk += 32) {
      bf16x8 a0 = sdoc8[(w * 16 + col) * 33 + (j0 + kk) / 8 + khi];
      #pragma unroll
      for (int nt = 0; nt < 4; ++nt) {
        bf16x8 bb = su8[(nt * 16 + col) * 9 + kk / 8 + khi];
        acc[nt] = MFMA(a0, bb, acc[nt]);
      }
    }
    __syncthreads();
  }

  // p = exp(s - m)/l * cw, split hi/lo bf16, transposed into [fh][n]
  #pragma unroll
  for (int nt = 0; nt < 4; ++nt) {
    int fh = nt * 16 + col;
    float m = sm_l[fh], li = sl_l[fh];
    #pragma unroll
    for (int r = 0; r < 4; ++r) {
      int n_loc = w * 16 + khi * 4 + r;
      float cv = scw[n_loc];
      float pv = __expf(acc[nt][r] * cv - m) * li * cv;
      u16 hi = f2b(pv);
      u16 lo = f2b(pv - b2f(hi));
      phu[fh * 72 + n_loc] = hi;
      plou[fh * 72 + n_loc] = lo;
    }
  }
  __syncthreads();

  // phase B: W[fh][j] += sum_n p[fh][n] * docs[n][j]; wave owns j-range w*64..+64
  f32x4 acc2[4][4];
  #pragma unroll
  for (int mt = 0; mt < 4; ++mt)
    #pragma unroll
    for (int nt = 0; nt < 4; ++nt) acc2[mt][nt] = (f32x4){0.f, 0.f, 0.f, 0.f};

  #pragma unroll
  for (int kk = 0; kk < 64; kk += 32) {
    bf16x8 ah[4], al[4];
    #pragma unroll
    for (int mt = 0; mt < 4; ++mt) {
      ah[mt] = ph8[(mt * 16 + col) * 9 + kk / 8 + khi];
      al[mt] = plo8[(mt * 16 + col) * 9 + kk / 8 + khi];
    }
    #pragma unroll
    for (int nt = 0; nt < 4; ++nt) {
      int j = w * 64 + nt * 16 + col;
      bf16x8 bb;
      #pragma unroll
      for (int jj = 0; jj < 8; ++jj)
        bb[jj] = (short)sdu[(kk + khi * 8 + jj) * 264 + j];
      #pragma unroll
      for (int mt = 0; mt < 4; ++mt) {
        acc2[mt][nt] = MFMA(ah[mt], bb, acc2[mt][nt]);
        acc2[mt][nt] = MFMA(al[mt], bb, acc2[mt][nt]);
      }
    }
  }
  #pragma unroll
  for (int mt = 0; mt < 4; ++mt)
    #pragma unroll
    for (int nt = 0; nt < 4; ++nt)
      #pragma unroll
      for (int r = 0; r < 4; ++r) {
        int fh = mt * 16 + khi * 4 + r;
        int j = w * 64 + nt * 16 + col;
        atomicAdd(&wbuf[((size_t)(b * 64) + fh) * H_ + j], acc2[mt][nt][r]);
      }
}

// =============== K5: ctx = Wv w + bv; ho = Wo ctx + bo; 3 meta steps =============
__global__ __launch_bounds__(256) void k5_headout(
    const float* __restrict__ ipw, const float* __restrict__ ipb,
    const float* __restrict__ opw, const float* __restrict__ opb,
    const float* __restrict__ meta, const float* __restrict__ wbuf,
    float* __restrict__ ho)
{
  const int f = blockIdx.x & 7, b = blockIdx.x >> 3;
  const int tid = threadIdx.x, L = tid & 63, w = tid >> 6;
  __shared__ float sw_[8 * H_];
  __shared__ float sctx[H_];
  __shared__ float sho[H_];
  #pragma unroll
  for (int i = 0; i < 8; ++i)
    sw_[i * H_ + tid] = wbuf[((size_t)(b * 64) + f * 8 + i) * H_ + tid];
  __syncthreads();
  for (int rr = 0; rr < 64; ++rr) {   // ctx rows, coalesced wave-per-row
    int r = w * 64 + rr;
    float4 a = *(const float4*)&ipw[((size_t)(f * 768 + 512) + r) * H_ + L * 4];
    float4 x = *(const float4*)&sw_[(r >> 5) * H_ + L * 4];
    float d = a.x * x.x + a.y * x.y + a.z * x.z + a.w * x.w;
    #pragma unroll
    for (int m = 32; m; m >>= 1) d += __shfl_xor(d, m, 64);
    if (L == rr) sctx[r] = d + ipb[f * 768 + 512 + r];
  }
  __syncthreads();
  {
    float4 x = *(const float4*)&sctx[L * 4];
    for (int rr = 0; rr < 64; ++rr) {   // ho rows
      int r = w * 64 + rr;
      float4 a = *(const float4*)&opw[((size_t)(f * H_) + r) * H_ + L * 4];
      float d = a.x * x.x + a.y * x.y + a.z * x.z + a.w * x.w;
      #pragma unroll
      for (int m = 32; m; m >>= 1) d += __shfl_xor(d, m, 64);
      if (L == rr) sho[r] = d + opb[f * H_ + r];
    }
  }
  __syncthreads();
  for (int s = 0; s < 3; ++s) {   // residual meta steps (meta reads coalesced)
    float acc = sho[tid];
    #pragma unroll 8
    for (int r = 0; r < H_; ++r) acc += sho[r] * meta[((size_t)(s * H_) + r) * H_ + tid];
    __syncthreads();
    sho[tid] = acc;
    __syncthreads();
  }
  ho[((size_t)(f * B_) + b) * H_ + tid] = sho[tid];
}

// =============== K6: strategy combine -> fp32 out ================================
__global__ __launch_bounds__(256) void k6_combine(
    const float* __restrict__ ho, const float* __restrict__ strat,
    float* __restrict__ out)
{
  const int b = blockIdx.x;
  const int tid = threadIdx.x;
  float acc = 0.f;
  #pragma unroll
  for (int f = 0; f < F_; ++f)
    acc += strat[b * F_ + f] * ho[((size_t)(f * B_) + b) * H_ + tid];
  out[b * H_ + tid] = acc;
}

extern "C" void kernel_launch(void* const* d_in, const int* in_sizes, int n_in,
                              void* d_out, int out_size, void* d_ws, size_t ws_size,
                              hipStream_t stream) {
  const float* query = (const float*)d_in[0];
  const float* docs  = (const float*)d_in[1];
  const float* cw    = (const float*)d_in[2];
  // d_in[3] context_history: unused by the reference
  const float* ipw   = (const float*)d_in[4];
  const float* ipb   = (const float*)d_in[5];
  const float* opw   = (const float*)d_in[6];
  const float* opb   = (const float*)d_in[7];
  const float* stw   = (const float*)d_in[8];
  const float* stb   = (const float*)d_in[9];
  const float* meta  = (const float*)d_in[10];
  float* out = (float*)d_out;

  char* base = (char*)d_ws;
  u16*   u     = (u16*)(base + UB_U);
  float* wbuf  = (float*)(base + UB_W);
  float* pm    = (float*)(base + UB_PM);
  float* pl    = (float*)(base + UB_PL);
  float* strat = (float*)(base + UB_STRAT);
  float* ho    = (float*)(base + UB_HO);

  hipMemsetAsync(wbuf, 0, (size_t)B_ * FH_ * H_ * sizeof(float), stream);
  k1_prep<<<dim3(F_ * B_), 256, 0, stream>>>(query, ipw, ipb, stw, stb, u, strat);
  k2_stats<<<dim3(NCH2_, B_), 256, 0, stream>>>(docs, cw, u, pm, pl);
  k4_waccum<<<dim3(32, B_), 256, 0, stream>>>(docs, cw, u, pm, pl, wbuf);
  k5_headout<<<dim3(F_ * B_), 256, 0, stream>>>(ipw, ipb, opw, opb, meta, wbuf, ho);
  k6_combine<<<dim3(B_), 256, 0, stream>>>(ho, strat, out);
}